// Round 1
// baseline (124.358 us; speedup 1.0000x reference)
//
#include <hip/hip_runtime.h>

#define BATCH 8
#define NPTS 16384
#define MSKEL 1000
#define NCLS 100
#define CKK 10
#define MINDIS_INITF 100000.0f

// ws layout (floats, 16B-aligned offsets):
//   skelN : float4[8000]     (-sx,-sy,-sz, 0.5|s|^2)   per (b,m)
//   ptsM  : float4[131072]   (x,y,z, 0.5|p|^2)         per (b,n)
//   mpart : float[128*8000]  per-(tile, b*1000+m) partial min of t
#define OFF_PTSM 32000
#define OFF_MPART (32000 + 524288)

// prep: build skelN and ptsM; zero output accumulator.
__global__ __launch_bounds__(256) void k_prep(const float* __restrict__ xyz,
                                              const float* __restrict__ skel,
                                              float4* __restrict__ skelN,
                                              float4* __restrict__ ptsM,
                                              float* __restrict__ out) {
    const int gid = blockIdx.x * 256 + threadIdx.x;  // 131072 threads exactly
    {
        const float* p = xyz + (size_t)gid * 6;
        float x = p[0], y = p[1], z = p[2];
        ptsM[gid] = make_float4(x, y, z, 0.5f * (x * x + y * y + z * z));
    }
    if (gid < BATCH * MSKEL) {
        const float* s = skel + (size_t)gid * 3;
        float sx = s[0], sy = s[1], sz = s[2];
        skelN[gid] = make_float4(-sx, -sy, -sz, 0.5f * (sx * sx + sy * sy + sz * sz));
    }
    if (gid == 0) out[0] = 0.0f;
}

// Merged chamfer: 1024 blocks (4/CU, 16 waves/CU), block = (b, 128-pt tile).
//   loop1 (n-side): each wave owns a 250-skel slice, each lane 2 points in
//                   regs; skel streamed via readfirstlane-forced s_load.
//                   Cross-wave min via LDS -> per-point sqrt -> block sum ->
//                   one atomicAdd (pre-scaled).
//   loop2 (m-side): 4 skel/thread in regs, streams the SAME 128-pt tile
//                   (block-uniform address -> s_load, L1-hot); writes
//                   per-tile partial mins to mpart (coalesced, no atomics).
__global__ __launch_bounds__(256, 4) void k_chamfer(const float4* __restrict__ skelN,
                                                    const float4* __restrict__ ptsM,
                                                    float* __restrict__ mpart,
                                                    float* __restrict__ out) {
    const int bid = blockIdx.x;           // 1024 = 8 batches * 128 tiles
    const int b = bid >> 7, gt = bid & 127;
    const int tid = threadIdx.x;
    const int wave = tid >> 6, lane = tid & 63;
    const float4* __restrict__ base = ptsM + b * NPTS + gt * 128;

    // loop2 skel registers (coalesced dwordx4)
    float nsx[4], nsy[4], nsz[4], mind[4];
#pragma unroll
    for (int k = 0; k < 4; ++k) {
        const int m = tid + k * 256;
        if (m < MSKEL) {
            float4 s = skelN[b * MSKEL + m];
            nsx[k] = s.x; nsy[k] = s.y; nsz[k] = s.z;  // already -s
        } else {
            nsx[k] = 0.0f; nsy[k] = 0.0f; nsz[k] = 0.0f;
        }
        mind[k] = 3.4e38f;
    }

    // loop1 points: all 4 waves hold the same 128-pt tile (2 pts/lane)
    float4 P0 = base[lane];
    float4 P1 = base[64 + lane];
    float mt0 = 3.4e38f, mt1 = 3.4e38f;

    const int w = __builtin_amdgcn_readfirstlane(wave);   // force scalar addr
    const float4* __restrict__ sk = skelN + b * MSKEL + w * 250;
#pragma unroll 5
    for (int m = 0; m < 250; ++m) {
        float4 s = sk[m];  // s_load_dwordx4, 8 VALU behind it
        float t0 = fmaf(P0.x, s.x, fmaf(P0.y, s.y, fmaf(P0.z, s.z, s.w)));
        float t1 = fmaf(P1.x, s.x, fmaf(P1.y, s.y, fmaf(P1.z, s.z, s.w)));
        mt0 = fminf(mt0, t0);
        mt1 = fminf(mt1, t1);
    }

    // combine the 4 wave-slices: sm[wave][pt] = mt + 0.5|p|^2
    __shared__ float sm[4 * 128];
    sm[wave * 128 + lane] = mt0 + P0.w;
    sm[wave * 128 + 64 + lane] = mt1 + P1.w;
    __syncthreads();

    float dsum = 0.0f;
    if (tid < 128) {
        float a = fminf(fminf(sm[tid], sm[128 + tid]),
                        fminf(sm[256 + tid], sm[384 + tid]));
        dsum = sqrtf(fmaxf(2.0f * a, 1e-12f));
    }

    // loop2: stream the same 128 points (block-uniform -> s_load, L1-hot)
#pragma unroll 8
    for (int n = 0; n < 128; ++n) {
        float4 r = base[n];
#pragma unroll
        for (int k = 0; k < 4; ++k) {
            // t = 0.5|p|^2 - p.s ; d^2 = 2t + |s|^2 (applied in k_reduce)
            float t = fmaf(r.x, nsx[k], fmaf(r.y, nsy[k], fmaf(r.z, nsz[k], r.w)));
            mind[k] = fminf(mind[k], t);
        }
    }
    float* __restrict__ mp = mpart + (size_t)gt * (BATCH * MSKEL) + b * MSKEL;
#pragma unroll
    for (int k = 0; k < 4; ++k) {
        const int m = tid + k * 256;
        if (m < MSKEL) mp[m] = mind[k];  // coalesced store, no atomics
    }

    // block-sum of the n-side sqrt terms
#pragma unroll
    for (int o = 32; o > 0; o >>= 1) dsum += __shfl_down(dsum, o, 64);
    __shared__ float s_part[4];
    if (lane == 0) s_part[wave] = dsum;
    __syncthreads();
    if (tid == 0) {
        atomicAdd(out, 0.0125f * (s_part[0] + s_part[1] + s_part[2] + s_part[3]));
    }
}

// reduce: fold 128 per-tile partial mins per (b,m) + convex-hull term.
__global__ __launch_bounds__(256) void k_reduce(const float* __restrict__ skel,
                                                const int* __restrict__ labels,
                                                const float4* __restrict__ skelN,
                                                const float* __restrict__ mpart,
                                                float* __restrict__ out) {
    const int gid = blockIdx.x * 256 + threadIdx.x;  // 32 blocks = 8192 threads
    const int tid = threadIdx.x;
    float acc = 0.0f;

    if (gid < BATCH * MSKEL) {
        float mind = 3.4e38f;
#pragma unroll 8
        for (int g = 0; g < 128; ++g) {
            mind = fminf(mind, mpart[g * (BATCH * MSKEL) + gid]);  // coalesced
        }
        float ssq = 2.0f * skelN[gid].w;          // |s|^2
        float d2 = fmaf(2.0f, mind, ssq);
        acc = 0.0125f * sqrtf(fmaxf(d2, 1e-12f));
    }

    if (gid < BATCH * NCLS) {
        const int b = gid / NCLS, c = gid - b * NCLS;
        const float* cp = skel + ((size_t)b * MSKEL + c * CKK) * 3;
        const int* lab = labels + (size_t)b * NCLS * CKK + c * CKK;
        float x[CKK], y[CKK], z[CKK];
        int lv[CKK];
#pragma unroll
        for (int i = 0; i < CKK; ++i) {
            x[i] = cp[i * 3 + 0]; y[i] = cp[i * 3 + 1]; z[i] = cp[i * 3 + 2];
            lv[i] = lab[i];
        }
        float convexSum = 0.0f;
#pragma unroll
        for (int i = 0; i < CKK; ++i) {
            if (lv[i] != 1) {
                float mindc = MINDIS_INITF;
#pragma unroll
                for (int j = 0; j < CKK; ++j) {
                    if (lv[j] == 1) {
                        float dx = x[i] - x[j], dy = y[i] - y[j], dz = z[i] - z[j];
                        mindc = fminf(mindc, dx * dx + dy * dy + dz * dz);
                    }
                }
                convexSum += mindc;
            }
        }
        acc += convexSum * (1.0f / (BATCH * NCLS));
    }

#pragma unroll
    for (int o = 32; o > 0; o >>= 1) acc += __shfl_down(acc, o, 64);
    __shared__ float s_part[4];
    const int wave = tid >> 6, lane = tid & 63;
    if (lane == 0) s_part[wave] = acc;
    __syncthreads();
    if (tid == 0) {
        atomicAdd(out, s_part[0] + s_part[1] + s_part[2] + s_part[3]);
    }
}

extern "C" void kernel_launch(void* const* d_in, const int* in_sizes, int n_in,
                              void* d_out, int out_size, void* d_ws, size_t ws_size,
                              hipStream_t stream) {
    const float* xyz = (const float*)d_in[0];
    const float* skel = (const float*)d_in[1];
    // d_in[2] = weights (unused by reference)
    const int* labels = (const int*)d_in[3];
    float* out = (float*)d_out;

    float4* skelN = (float4*)d_ws;
    float4* ptsM = (float4*)((float*)d_ws + OFF_PTSM);
    float* mpart = (float*)d_ws + OFF_MPART;

    k_prep<<<512, 256, 0, stream>>>(xyz, skel, skelN, ptsM, out);
    k_chamfer<<<1024, 256, 0, stream>>>(skelN, ptsM, mpart, out);
    k_reduce<<<32, 256, 0, stream>>>(skel, labels, skelN, mpart, out);
}

// Round 2
// 95.953 us; speedup vs baseline: 1.2960x; 1.2960x over previous
//
#include <hip/hip_runtime.h>

#define BATCH 8
#define NPTS 16384
#define MSKEL 1000
#define NCLS 100
#define CKK 10
#define MINDIS_INITF 100000.0f

// ws layout (16B aligned):
//   skelN  : float4[8000]   (-sx,-sy,-sz, 0.5|s|^2) per (b,m)
//   ptsM   : float4[131072] (x,y,z, 0.5|p|^2)       per (b,n)
//   minbits: uint[8000]     per-(b,m) min d^2 as uint bits
#define OFF_PTSM 32000
#define OFF_MINB (32000 + 524288)

// prep: build skelN and ptsM; init minbits to +inf; zero output accumulator.
__global__ __launch_bounds__(256) void k_prep(const float* __restrict__ xyz,
                                              const float* __restrict__ skel,
                                              float4* __restrict__ skelN,
                                              float4* __restrict__ ptsM,
                                              unsigned int* __restrict__ minbits,
                                              float* __restrict__ out) {
    const int gid = blockIdx.x * 256 + threadIdx.x;  // 131072 threads exactly
    {
        const float* p = xyz + (size_t)gid * 6;
        float x = p[0], y = p[1], z = p[2];
        ptsM[gid] = make_float4(x, y, z, 0.5f * (x * x + y * y + z * z));
    }
    if (gid < BATCH * MSKEL) {
        const float* s = skel + (size_t)gid * 3;
        float sx = s[0], sy = s[1], sz = s[2];
        skelN[gid] = make_float4(-sx, -sy, -sz, 0.5f * (sx * sx + sy * sy + sz * sz));
        minbits[gid] = 0x7F800000u;  // +inf
    }
    if (gid == 0) out[0] = 0.0f;
}

// Fused chamfer, 512 blocks x 512 threads (2 blocks/CU, 16 waves/CU,
// 4 waves/SIMD — double round-0 latency-hiding depth at IDENTICAL per-load
// instruction mix).
//   blocks [0,256):   n-side — 512-pt tile; each LANE owns 8 points, each
//                     of the 8 WAVES owns a 125-skel slice → 32 VALU per
//                     uniform load. Cross-wave min via LDS (8 slices),
//                     block-sum, one atomicAdd (pre-scaled).
//   blocks [256,512): m-side — 4 skel/thread in regs; the two 256-thread
//                     halves stream disjoint 256-pt halves of the tile
//                     uniformly (16 VALU per load); atomicMin(minbits).
__global__ __launch_bounds__(512, 4) void k_chamfer(const float4* __restrict__ skelN,
                                                    const float4* __restrict__ ptsM,
                                                    unsigned int* __restrict__ minbits,
                                                    float* __restrict__ out) {
    const int bid = blockIdx.x;
    const int tid = threadIdx.x;
    const int wave = tid >> 6, lane = tid & 63;

    if (bid < 256) {
        // ---------------- n-side ----------------
        const int b = bid >> 5, tile = bid & 31;
        const float4* __restrict__ base = ptsM + b * NPTS + tile * 512;

        float4 P[8];
        float mt[8];
#pragma unroll
        for (int j = 0; j < 8; ++j) {
            P[j] = base[j * 64 + lane];  // coalesced dwordx4 (same in all waves, L1-hot)
            mt[j] = 3.4e38f;
        }

        const float4* __restrict__ sk = skelN + b * MSKEL + wave * 125;
#pragma unroll 5
        for (int m = 0; m < 125; ++m) {
            float4 s = sk[m];  // wave-uniform stream, 32 VALU inst behind it
#pragma unroll
            for (int j = 0; j < 8; ++j) {
                float t = fmaf(P[j].x, s.x, fmaf(P[j].y, s.y, fmaf(P[j].z, s.z, s.w)));
                mt[j] = fminf(mt[j], t);
            }
        }

        // combine across the 8 wave-slices: sm[wave][pt] = mt + 0.5|p|^2
        __shared__ float sm[8 * 512];
#pragma unroll
        for (int j = 0; j < 8; ++j) {
            sm[wave * 512 + j * 64 + lane] = mt[j] + P[j].w;
        }
        __syncthreads();

        // thread tid finalizes point tid (512 threads, 512 points)
        float a = sm[tid];
#pragma unroll
        for (int w = 1; w < 8; ++w) a = fminf(a, sm[w * 512 + tid]);
        float d = sqrtf(fmaxf(2.0f * a, 1e-12f));

#pragma unroll
        for (int o = 32; o > 0; o >>= 1) d += __shfl_down(d, o, 64);
        __shared__ float s_part[8];
        if (lane == 0) s_part[wave] = d;
        __syncthreads();
        if (tid == 0) {
            float t = 0.0f;
#pragma unroll
            for (int w = 0; w < 8; ++w) t += s_part[w];
            atomicAdd(out, 0.0125f * t);
        }
    } else {
        // ---------------- m-side ----------------
        const int id = bid - 256;
        const int b = id >> 5, tile = id & 31;
        const int half = tid >> 8, ts = tid & 255;

        float nsx[4], nsy[4], nsz[4], ssq[4], mind[4];
#pragma unroll
        for (int k = 0; k < 4; ++k) {
            const int m = ts + k * 256;
            if (m < MSKEL) {
                float4 s = skelN[b * MSKEL + m];  // coalesced
                nsx[k] = s.x; nsy[k] = s.y; nsz[k] = s.z;  // already -s
                ssq[k] = 2.0f * s.w;                        // |s|^2
            } else {
                nsx[k] = 0.0f; nsy[k] = 0.0f; nsz[k] = 0.0f; ssq[k] = 0.0f;
            }
            mind[k] = 3.4e38f;
        }

        const float4* __restrict__ pp = ptsM + b * NPTS + tile * 512 + half * 256;
#pragma unroll 8
        for (int n = 0; n < 256; ++n) {
            float4 r = pp[n];  // half-uniform stream, 16 VALU inst behind it
#pragma unroll
            for (int k = 0; k < 4; ++k) {
                // t = 0.5|p|^2 - p.s ; d^2 = 2t + |s|^2
                float t = fmaf(r.x, nsx[k], fmaf(r.y, nsy[k], fmaf(r.z, nsz[k], r.w)));
                mind[k] = fminf(mind[k], t);
            }
        }
#pragma unroll
        for (int k = 0; k < 4; ++k) {
            const int m = ts + k * 256;
            if (m < MSKEL) {
                float d2 = fmaf(2.0f, mind[k], ssq[k]);
                // clamp fp-cancellation negatives so uint order == float order
                atomicMin(&minbits[b * MSKEL + m], __float_as_uint(fmaxf(d2, 0.0f)));
            }
        }
    }
}

// reduce: m-side mins (32 KB) + convex-hull term; atomicAdd into out.
__global__ __launch_bounds__(256) void k_reduce(const float* __restrict__ skel,
                                                const int* __restrict__ labels,
                                                const unsigned int* __restrict__ minbits,
                                                float* __restrict__ out) {
    const int gid = blockIdx.x * 256 + threadIdx.x;  // 8 blocks = 2048 threads
    const int tid = threadIdx.x;
    float acc = 0.0f;

    for (int i = gid; i < BATCH * MSKEL; i += 2048) {
        acc += 0.0125f * sqrtf(fmaxf(__uint_as_float(minbits[i]), 1e-12f));
    }

    if (gid < BATCH * NCLS) {
        const int b = gid / NCLS, c = gid - b * NCLS;
        const float* cp = skel + ((size_t)b * MSKEL + c * CKK) * 3;
        const int* lab = labels + (size_t)b * NCLS * CKK + c * CKK;
        float x[CKK], y[CKK], z[CKK];
        int lv[CKK];
#pragma unroll
        for (int i = 0; i < CKK; ++i) {
            x[i] = cp[i * 3 + 0]; y[i] = cp[i * 3 + 1]; z[i] = cp[i * 3 + 2];
            lv[i] = lab[i];
        }
        float convexSum = 0.0f;
#pragma unroll
        for (int i = 0; i < CKK; ++i) {
            if (lv[i] != 1) {
                float mind = MINDIS_INITF;
#pragma unroll
                for (int j = 0; j < CKK; ++j) {
                    if (lv[j] == 1) {
                        float dx = x[i] - x[j], dy = y[i] - y[j], dz = z[i] - z[j];
                        mind = fminf(mind, dx * dx + dy * dy + dz * dz);
                    }
                }
                convexSum += mind;
            }
        }
        acc += convexSum * (1.0f / (BATCH * NCLS));
    }

#pragma unroll
    for (int o = 32; o > 0; o >>= 1) acc += __shfl_down(acc, o, 64);
    __shared__ float s_part[4];
    const int wave = tid >> 6, lane = tid & 63;
    if (lane == 0) s_part[wave] = acc;
    __syncthreads();
    if (tid == 0) {
        atomicAdd(out, s_part[0] + s_part[1] + s_part[2] + s_part[3]);
    }
}

extern "C" void kernel_launch(void* const* d_in, const int* in_sizes, int n_in,
                              void* d_out, int out_size, void* d_ws, size_t ws_size,
                              hipStream_t stream) {
    const float* xyz = (const float*)d_in[0];
    const float* skel = (const float*)d_in[1];
    // d_in[2] = weights (unused by reference)
    const int* labels = (const int*)d_in[3];
    float* out = (float*)d_out;

    float4* skelN = (float4*)d_ws;
    float4* ptsM = (float4*)((float*)d_ws + OFF_PTSM);
    unsigned int* minbits = (unsigned int*)((float*)d_ws + OFF_MINB);

    k_prep<<<512, 256, 0, stream>>>(xyz, skel, skelN, ptsM, minbits, out);
    k_chamfer<<<512, 512, 0, stream>>>(skelN, ptsM, minbits, out);
    k_reduce<<<8, 256, 0, stream>>>(skel, labels, minbits, out);
}

// Round 4
// 95.862 us; speedup vs baseline: 1.2973x; 1.0009x over previous
//
#include <hip/hip_runtime.h>

#define BATCH 8
#define NPTS 16384
#define MSKEL 1000
#define NCLS 100
#define CKK 10
#define MINDIS_INITF 100000.0f

// ws layout (floats):
//   mpart : float[32*8000]  per-(tile, b*1000+m) partial min of t   @ 0
//   npart : float[256]      per-n-block raw sum of d                @ 256000
#define OFF_NPART 256000

// Kernel A: fused prep + chamfer. 512 blocks x 256 threads (2 blocks/CU).
//   blocks [0,256):   n-side — block (b,tile): stage all 1000 skels of batch
//                     b into LDS as (-s, 0.5|s|^2) float4; 512-pt tile in
//                     regs (8/lane, computed from raw xyz); each of 4 waves
//                     streams a 250-skel LDS slice (ds_read_b128 broadcast,
//                     32 VALU behind each); LDS combine; sqrt; block sum ->
//                     plain store to npart[bid]. No atomics.
//   blocks [256,512): m-side — block (b,tile): stage its 512-pt tile into
//                     LDS (computed from raw xyz); 4 skels/thread in regs
//                     (from raw skel); stream 512 pts from LDS (16 VALU per
//                     ds_read); coalesced stores to mpart. No atomics.
//   bid 0, tid 0 zeroes out[0] (kernel B is stream-ordered after A).
__global__ __launch_bounds__(256) void k_A(const float* __restrict__ xyz,
                                           const float* __restrict__ skel,
                                           float* __restrict__ mpart,
                                           float* __restrict__ npart,
                                           float* __restrict__ out) {
    const int bid = blockIdx.x;
    const int tid = threadIdx.x;
    const int wave = tid >> 6, lane = tid & 63;

    if (bid == 0 && tid == 0) out[0] = 0.0f;

    if (bid < 256) {
        // ---------------- n-side ----------------
        const int b = bid >> 5, tile = bid & 31;

        __shared__ float4 skLDS[MSKEL];   // 16 KB
        __shared__ float sm[4 * 512];     //  8 KB
        __shared__ float s_part[4];

        // stage skels: (-sx,-sy,-sz, 0.5|s|^2)
        for (int i = tid; i < MSKEL; i += 256) {
            const float* s = skel + ((size_t)b * MSKEL + i) * 3;
            float sx = s[0], sy = s[1], sz = s[2];
            skLDS[i] = make_float4(-sx, -sy, -sz, 0.5f * (sx * sx + sy * sy + sz * sz));
        }

        // tile points in regs: (x,y,z) + 0.5|p|^2
        float4 P[8];
        float mt[8];
#pragma unroll
        for (int j = 0; j < 8; ++j) {
            const float* p = xyz + ((size_t)b * NPTS + tile * 512 + j * 64 + lane) * 6;
            float x = p[0], y = p[1], z = p[2];
            P[j] = make_float4(x, y, z, 0.5f * (x * x + y * y + z * z));
            mt[j] = 3.4e38f;
        }
        __syncthreads();

        const float4* __restrict__ sk = &skLDS[wave * 250];
#pragma unroll 5
        for (int m = 0; m < 250; ++m) {
            float4 s = sk[m];  // ds_read_b128, wave-uniform broadcast; 32 VALU behind
#pragma unroll
            for (int j = 0; j < 8; ++j) {
                float t = fmaf(P[j].x, s.x, fmaf(P[j].y, s.y, fmaf(P[j].z, s.z, s.w)));
                mt[j] = fminf(mt[j], t);
            }
        }

        // combine across the 4 wave-slices: sm[wave][pt] = mt + 0.5|p|^2
#pragma unroll
        for (int j = 0; j < 8; ++j) {
            sm[wave * 512 + j * 64 + lane] = mt[j] + P[j].w;
        }
        __syncthreads();

        // thread tid finalizes points tid and tid+256
        float a0 = fminf(fminf(sm[tid], sm[512 + tid]),
                         fminf(sm[1024 + tid], sm[1536 + tid]));
        float a1 = fminf(fminf(sm[tid + 256], sm[512 + tid + 256]),
                         fminf(sm[1024 + tid + 256], sm[1536 + tid + 256]));
        float d = sqrtf(fmaxf(2.0f * a0, 1e-12f)) + sqrtf(fmaxf(2.0f * a1, 1e-12f));

#pragma unroll
        for (int o = 32; o > 0; o >>= 1) d += __shfl_down(d, o, 64);
        if (lane == 0) s_part[wave] = d;
        __syncthreads();
        if (tid == 0) {
            npart[bid] = s_part[0] + s_part[1] + s_part[2] + s_part[3];  // raw sum
        }
    } else {
        // ---------------- m-side ----------------
        const int id = bid - 256;
        const int b = id >> 5, tile = id & 31;

        __shared__ float4 ptLDS[512];     // 8 KB

        // stage tile points: (x,y,z, 0.5|p|^2), 2 per thread
#pragma unroll
        for (int j = 0; j < 2; ++j) {
            const int n = tid * 2 + j;
            const float* p = xyz + ((size_t)b * NPTS + tile * 512 + n) * 6;
            float x = p[0], y = p[1], z = p[2];
            ptLDS[n] = make_float4(x, y, z, 0.5f * (x * x + y * y + z * z));
        }

        // 4 skels/thread in regs from raw skel
        float nsx[4], nsy[4], nsz[4], mind[4];
#pragma unroll
        for (int k = 0; k < 4; ++k) {
            const int m = tid + k * 256;
            if (m < MSKEL) {
                const float* s = skel + ((size_t)b * MSKEL + m) * 3;
                nsx[k] = -s[0]; nsy[k] = -s[1]; nsz[k] = -s[2];
            } else {
                nsx[k] = 0.0f; nsy[k] = 0.0f; nsz[k] = 0.0f;
            }
            mind[k] = 3.4e38f;
        }
        __syncthreads();

#pragma unroll 8
        for (int n = 0; n < 512; ++n) {
            float4 r = ptLDS[n];  // ds_read_b128 broadcast; 16 VALU behind
#pragma unroll
            for (int k = 0; k < 4; ++k) {
                // t = 0.5|p|^2 - p.s  (0.5|s|^2 added in kernel B)
                float t = fmaf(r.x, nsx[k], fmaf(r.y, nsy[k], fmaf(r.z, nsz[k], r.w)));
                mind[k] = fminf(mind[k], t);
            }
        }
#pragma unroll
        for (int k = 0; k < 4; ++k) {
            const int m = tid + k * 256;
            if (m < MSKEL) {
                mpart[(size_t)tile * (BATCH * MSKEL) + b * MSKEL + m] = mind[k];  // coalesced
            }
        }
    }
}

// Kernel B: fold 32 m-partials per (b,m) (+0.5|s|^2, sqrt), hull term,
// n-partial sums; single atomicAdd per block into out (zeroed by A).
__global__ __launch_bounds__(256) void k_B(const float* __restrict__ skel,
                                           const int* __restrict__ labels,
                                           const float* __restrict__ mpart,
                                           const float* __restrict__ npart,
                                           float* __restrict__ out) {
    const int gid = blockIdx.x * 256 + threadIdx.x;  // 32 blocks = 8192 threads
    const int tid = threadIdx.x;
    float acc = 0.0f;

    if (gid < BATCH * MSKEL) {
        float mind = 3.4e38f;
#pragma unroll 8
        for (int g = 0; g < 32; ++g) {
            mind = fminf(mind, mpart[(size_t)g * (BATCH * MSKEL) + gid]);  // coalesced
        }
        const float* s = skel + (size_t)gid * 3;
        float sx = s[0], sy = s[1], sz = s[2];
        float d2 = fmaf(2.0f, mind, sx * sx + sy * sy + sz * sz);
        acc = 0.0125f * sqrtf(fmaxf(d2, 1e-12f));
    }

    if (gid < BATCH * NCLS) {
        const int b = gid / NCLS, c = gid - b * NCLS;
        const float* cp = skel + ((size_t)b * MSKEL + c * CKK) * 3;
        const int* lab = labels + (size_t)b * NCLS * CKK + c * CKK;
        float x[CKK], y[CKK], z[CKK];
        int lv[CKK];
#pragma unroll
        for (int i = 0; i < CKK; ++i) {
            x[i] = cp[i * 3 + 0]; y[i] = cp[i * 3 + 1]; z[i] = cp[i * 3 + 2];
            lv[i] = lab[i];
        }
        float convexSum = 0.0f;
#pragma unroll
        for (int i = 0; i < CKK; ++i) {
            if (lv[i] != 1) {
                float mindc = MINDIS_INITF;
#pragma unroll
                for (int j = 0; j < CKK; ++j) {
                    if (lv[j] == 1) {
                        float dx = x[i] - x[j], dy = y[i] - y[j], dz = z[i] - z[j];
                        mindc = fminf(mindc, dx * dx + dy * dy + dz * dz);
                    }
                }
                convexSum += mindc;
            }
        }
        acc += convexSum * (1.0f / (BATCH * NCLS));
    }

    if (blockIdx.x == 0) {
        acc += 0.0125f * npart[tid];  // 256 n-block raw sums
    }

#pragma unroll
    for (int o = 32; o > 0; o >>= 1) acc += __shfl_down(acc, o, 64);
    __shared__ float s_part[4];
    const int wave = tid >> 6, lane = tid & 63;
    if (lane == 0) s_part[wave] = acc;
    __syncthreads();
    if (tid == 0) {
        atomicAdd(out, s_part[0] + s_part[1] + s_part[2] + s_part[3]);
    }
}

extern "C" void kernel_launch(void* const* d_in, const int* in_sizes, int n_in,
                              void* d_out, int out_size, void* d_ws, size_t ws_size,
                              hipStream_t stream) {
    const float* xyz = (const float*)d_in[0];
    const float* skel = (const float*)d_in[1];
    // d_in[2] = weights (unused by reference)
    const int* labels = (const int*)d_in[3];
    float* out = (float*)d_out;

    float* mpart = (float*)d_ws;
    float* npart = (float*)d_ws + OFF_NPART;

    k_A<<<512, 256, 0, stream>>>(xyz, skel, mpart, npart, out);
    k_B<<<32, 256, 0, stream>>>(skel, labels, mpart, npart, out);
}

// Round 5
// 94.605 us; speedup vs baseline: 1.3145x; 1.0133x over previous
//
#include <hip/hip_runtime.h>

#define BATCH 8
#define NPTS 16384
#define MSKEL 1000
#define NCLS 100
#define CKK 10
#define MINDIS_INITF 100000.0f

// ws layout (16B aligned):
//   skelN  : float4[8000]   (-sx,-sy,-sz, 0.5|s|^2) per (b,m)
//   ptsM   : float4[131072] (x,y,z, 0.5|p|^2)       per (b,n)
//   minbits: uint[8000]     per-(b,m) min d^2 as uint bits
#define OFF_PTSM 32000
#define OFF_MINB (32000 + 524288)

// prep: build skelN and ptsM; init minbits to +inf; zero output accumulator.
__global__ __launch_bounds__(256) void k_prep(const float* __restrict__ xyz,
                                              const float* __restrict__ skel,
                                              float4* __restrict__ skelN,
                                              float4* __restrict__ ptsM,
                                              unsigned int* __restrict__ minbits,
                                              float* __restrict__ out) {
    const int gid = blockIdx.x * 256 + threadIdx.x;  // 131072 threads exactly
    {
        const float* p = xyz + (size_t)gid * 6;
        float x = p[0], y = p[1], z = p[2];
        ptsM[gid] = make_float4(x, y, z, 0.5f * (x * x + y * y + z * z));
    }
    if (gid < BATCH * MSKEL) {
        const float* s = skel + (size_t)gid * 3;
        float sx = s[0], sy = s[1], sz = s[2];
        skelN[gid] = make_float4(-sx, -sy, -sz, 0.5f * (sx * sx + sy * sy + sz * sz));
        minbits[gid] = 0x7F800000u;  // +inf
    }
    if (gid == 0) out[0] = 0.0f;
}

// Fused chamfer, 512 blocks (2/CU).
//   blocks [0,256):   n-side — 512-pt tile; each LANE owns 8 points (pt =
//                     j*64+lane), each WAVE owns a 250-skel slice → 32 VALU
//                     per uniform s_load (latency fully hidden, 4x fewer
//                     scalar loads). Cross-wave min via LDS, block-sum,
//                     one atomicAdd into out (pre-scaled).
//   blocks [256,512): m-side — 4 skel/thread in regs, 512-pt tile uniform
//                     stream; d^2 = 2*min_t + |s|^2 → atomicMin(minbits).
__global__ __launch_bounds__(256) void k_chamfer(const float4* __restrict__ skelN,
                                                 const float4* __restrict__ ptsM,
                                                 unsigned int* __restrict__ minbits,
                                                 float* __restrict__ out) {
    const int bid = blockIdx.x;
    const int tid = threadIdx.x;

    if (bid < 256) {
        // ---------------- n-side ----------------
        const int b = bid >> 5, tile = bid & 31;
        const int wave = tid >> 6, lane = tid & 63;
        const float4* __restrict__ base = ptsM + b * NPTS + tile * 512;

        float4 P[8];
        float mt[8];
#pragma unroll
        for (int j = 0; j < 8; ++j) {
            P[j] = base[j * 64 + lane];  // coalesced dwordx4
            mt[j] = 3.4e38f;
        }

        const float4* __restrict__ sk = skelN + b * MSKEL + wave * 250;
#pragma unroll 5
        for (int m = 0; m < 250; ++m) {
            float4 s = sk[m];  // uniform -> s_load_dwordx4, 32 VALU inst behind it
#pragma unroll
            for (int j = 0; j < 8; ++j) {
                float t = fmaf(P[j].x, s.x, fmaf(P[j].y, s.y, fmaf(P[j].z, s.z, s.w)));
                mt[j] = fminf(mt[j], t);
            }
        }

        // combine across the 4 wave-slices: sm[wave][pt] = mt + 0.5|p|^2
        __shared__ float sm[4 * 512];
#pragma unroll
        for (int j = 0; j < 8; ++j) {
            sm[wave * 512 + j * 64 + lane] = mt[j] + P[j].w;
        }
        __syncthreads();

        // thread tid finalizes points tid and tid+256
        float a0 = fminf(fminf(sm[tid], sm[512 + tid]),
                         fminf(sm[1024 + tid], sm[1536 + tid]));
        float a1 = fminf(fminf(sm[tid + 256], sm[512 + tid + 256]),
                         fminf(sm[1024 + tid + 256], sm[1536 + tid + 256]));
        float d = sqrtf(fmaxf(2.0f * a0, 1e-12f)) + sqrtf(fmaxf(2.0f * a1, 1e-12f));

#pragma unroll
        for (int o = 32; o > 0; o >>= 1) d += __shfl_down(d, o, 64);
        __shared__ float s_part[4];
        if (lane == 0) s_part[wave] = d;
        __syncthreads();
        if (tid == 0) {
            atomicAdd(out, 0.0125f * (s_part[0] + s_part[1] + s_part[2] + s_part[3]));
        }
    } else {
        // ---------------- m-side ----------------
        const int id = bid - 256;
        const int b = id >> 5, tile = id & 31;

        float nsx[4], nsy[4], nsz[4], ssq[4], mind[4];
#pragma unroll
        for (int k = 0; k < 4; ++k) {
            const int m = tid + k * 256;
            if (m < MSKEL) {
                float4 s = skelN[b * MSKEL + m];  // coalesced
                nsx[k] = s.x; nsy[k] = s.y; nsz[k] = s.z;  // already -s
                ssq[k] = 2.0f * s.w;                        // |s|^2
            } else {
                nsx[k] = 0.0f; nsy[k] = 0.0f; nsz[k] = 0.0f; ssq[k] = 0.0f;
            }
            mind[k] = 3.4e38f;
        }

        const float4* __restrict__ pp = ptsM + b * NPTS + tile * 512;
#pragma unroll 8
        for (int n = 0; n < 512; ++n) {
            float4 r = pp[n];  // uniform -> s_load_dwordx4
#pragma unroll
            for (int k = 0; k < 4; ++k) {
                // t = 0.5|p|^2 - p.s ; d^2 = 2t + |s|^2
                float t = fmaf(r.x, nsx[k], fmaf(r.y, nsy[k], fmaf(r.z, nsz[k], r.w)));
                mind[k] = fminf(mind[k], t);
            }
        }
#pragma unroll
        for (int k = 0; k < 4; ++k) {
            const int m = tid + k * 256;
            if (m < MSKEL) {
                float d2 = fmaf(2.0f, mind[k], ssq[k]);
                // clamp fp-cancellation negatives so uint order == float order
                atomicMin(&minbits[b * MSKEL + m], __float_as_uint(fmaxf(d2, 0.0f)));
            }
        }
    }
}

// reduce: m-side mins (32 KB) + convex-hull term; atomicAdd into out.
__global__ __launch_bounds__(256) void k_reduce(const float* __restrict__ skel,
                                                const int* __restrict__ labels,
                                                const unsigned int* __restrict__ minbits,
                                                float* __restrict__ out) {
    const int gid = blockIdx.x * 256 + threadIdx.x;  // 8 blocks = 2048 threads
    const int tid = threadIdx.x;
    float acc = 0.0f;

    for (int i = gid; i < BATCH * MSKEL; i += 2048) {
        acc += 0.0125f * sqrtf(fmaxf(__uint_as_float(minbits[i]), 1e-12f));
    }

    if (gid < BATCH * NCLS) {
        const int b = gid / NCLS, c = gid - b * NCLS;
        const float* cp = skel + ((size_t)b * MSKEL + c * CKK) * 3;
        const int* lab = labels + (size_t)b * NCLS * CKK + c * CKK;
        float x[CKK], y[CKK], z[CKK];
        int lv[CKK];
#pragma unroll
        for (int i = 0; i < CKK; ++i) {
            x[i] = cp[i * 3 + 0]; y[i] = cp[i * 3 + 1]; z[i] = cp[i * 3 + 2];
            lv[i] = lab[i];
        }
        float convexSum = 0.0f;
#pragma unroll
        for (int i = 0; i < CKK; ++i) {
            if (lv[i] != 1) {
                float mind = MINDIS_INITF;
#pragma unroll
                for (int j = 0; j < CKK; ++j) {
                    if (lv[j] == 1) {
                        float dx = x[i] - x[j], dy = y[i] - y[j], dz = z[i] - z[j];
                        mind = fminf(mind, dx * dx + dy * dy + dz * dz);
                    }
                }
                convexSum += mind;
            }
        }
        acc += convexSum * (1.0f / (BATCH * NCLS));
    }

#pragma unroll
    for (int o = 32; o > 0; o >>= 1) acc += __shfl_down(acc, o, 64);
    __shared__ float s_part[4];
    const int wave = tid >> 6, lane = tid & 63;
    if (lane == 0) s_part[wave] = acc;
    __syncthreads();
    if (tid == 0) {
        atomicAdd(out, s_part[0] + s_part[1] + s_part[2] + s_part[3]);
    }
}

extern "C" void kernel_launch(void* const* d_in, const int* in_sizes, int n_in,
                              void* d_out, int out_size, void* d_ws, size_t ws_size,
                              hipStream_t stream) {
    const float* xyz = (const float*)d_in[0];
    const float* skel = (const float*)d_in[1];
    // d_in[2] = weights (unused by reference)
    const int* labels = (const int*)d_in[3];
    float* out = (float*)d_out;

    float4* skelN = (float4*)d_ws;
    float4* ptsM = (float4*)((float*)d_ws + OFF_PTSM);
    unsigned int* minbits = (unsigned int*)((float*)d_ws + OFF_MINB);

    k_prep<<<512, 256, 0, stream>>>(xyz, skel, skelN, ptsM, minbits, out);
    k_chamfer<<<512, 256, 0, stream>>>(skelN, ptsM, minbits, out);
    k_reduce<<<8, 256, 0, stream>>>(skel, labels, minbits, out);
}